// Round 7
// baseline (885.172 us; speedup 1.0000x reference)
//
#include <hip/hip_runtime.h>
#include <hip/hip_bf16.h>

#define TOKENS 32768
#define NEXP   16
#define HID    2048
#define IMD    1408
#define BM 256
#define BK 64

typedef __bf16 bf16x8 __attribute__((ext_vector_type(8)));
typedef float  f32x4  __attribute__((ext_vector_type(4)));
typedef unsigned short u16x8 __attribute__((ext_vector_type(8)));

using gptr1_t = const __attribute__((address_space(1))) void*;
using lptr3_t = __attribute__((address_space(3))) void*;

static __device__ __forceinline__ unsigned short f2bf(float f) {
  unsigned int x = __builtin_bit_cast(unsigned int, f);
  x += 0x7fffu + ((x >> 16) & 1u);   // round-to-nearest-even
  return (unsigned short)(x >> 16);
}
static __device__ __forceinline__ float bf2f(unsigned short u) {
  unsigned int x = ((unsigned int)u) << 16;
  return __builtin_bit_cast(float, x);
}
static __device__ __forceinline__ void gload16(const void* g, void* l) {
  __builtin_amdgcn_global_load_lds((gptr1_t)g, (lptr3_t)l, 16, 0, 0);
}
static __device__ __forceinline__ void vwait(int n) {
  switch (n) {
    case 0:  asm volatile("s_waitcnt vmcnt(0)" ::: "memory"); break;
    case 2:  asm volatile("s_waitcnt vmcnt(2)" ::: "memory"); break;
    default: asm volatile("s_waitcnt vmcnt(6)" ::: "memory"); break;
  }
}
static __device__ __forceinline__ void lg0sb() {
  asm volatile("s_waitcnt lgkmcnt(0)" ::: "memory");
  __builtin_amdgcn_sched_barrier(0);
}

// ---------------- f32 -> bf16 straight convert (x) ----------------
__global__ __launch_bounds__(256)
void convert_kernel(const float* __restrict__ in, unsigned short* __restrict__ out, size_t n)
{
  size_t i = ((size_t)blockIdx.x * blockDim.x + threadIdx.x) * 8;
  if (i >= n) return;
  float4 a = *(const float4*)(in + i);
  float4 b = *(const float4*)(in + i + 4);
  u16x8 o;
  o[0] = f2bf(a.x); o[1] = f2bf(a.y); o[2] = f2bf(a.z); o[3] = f2bf(a.w);
  o[4] = f2bf(b.x); o[5] = f2bf(b.y); o[6] = f2bf(b.z); o[7] = f2bf(b.w);
  *(u16x8*)(out + i) = o;
}

// ------------- f32 [E][K][N] -> bf16 [E][N][K] transpose-convert -------------
__global__ __launch_bounds__(256)
void transpose_conv_kernel(const float* __restrict__ in, unsigned short* __restrict__ out,
                           int K, int N)
{
  __shared__ float tile[32][33];
  const int e = blockIdx.z;
  const float* ip = in + (size_t)e * K * N;
  unsigned short* op = out + (size_t)e * K * N;
  const int c0 = blockIdx.x * 32, r0 = blockIdx.y * 32;
  const int tx = threadIdx.x, ty = threadIdx.y;
#pragma unroll
  for (int i = 0; i < 4; ++i)
    tile[ty + 8 * i][tx] = ip[(size_t)(r0 + ty + 8 * i) * N + c0 + tx];
  __syncthreads();
#pragma unroll
  for (int i = 0; i < 4; ++i)
    op[(size_t)(c0 + ty + 8 * i) * K + r0 + tx] = f2bf(tile[tx][ty + 8 * i]);
}

// ======== grouped GEMM, 256x256, BK=64, 3-phase ledgered pipeline ========
// Phases per K-tile (2M x 4N waves, 16x16x32 MFMA, per-wave 128x64):
//  ph0 (mh0,kk0): 8 ds_read | stage A-c2 + B-c0 (t+1) | BAR lgkm0 16 MFMA BAR
//  ph1 (mh0,kk1): 8 ds_read | stage B-c1 (t+1)        | BAR lgkm0 16 MFMA vmcnt(6) BAR
//  ph2 (mh1,kk0+1): 8 ds_read | stage A-c3 (t+1)      | BAR lgkm0 32 MFMA vmcnt(2) BAR
// Ledger (steady state, 2 loads/chunk): after ph2-wait exactly c3(t) in flight;
// ph0 +4, ph1 +2 -> vmcnt(6) drains c3(t) [cover 2 phases]; ph2 +2 -> vmcnt(2)
// drains c2,c0,c1(t+1) [A-covers 2 phases; 1-phase chunk is L2-warm B].
// LDS: identity row layout, slot swizzle s_phys = s_log ^ (row&7), staged via
// pre-swizzled source column (both sides, rule #21; r4-proven 0-conflict).
// MODE 0: fused gate+up, B rows interleaved 16 (even blk=gate, odd=up):
//         h = bf16(silu(g)*u). MODE 1: down, BN=256, f32 out.
template<int MODE, int K, int N>
__global__ __launch_bounds__(512, 2)
void gemm_kernel(const unsigned short* __restrict__ A,
                 const unsigned short* __restrict__ B0m,
                 const unsigned short* __restrict__ B1m,
                 unsigned short* __restrict__ Hc,
                 float* __restrict__ Cf,
                 const int* __restrict__ gs)
{
  constexpr int NRT = TOKENS / BM;
  constexpr int nt  = K / BK;

  __shared__ __align__(16) unsigned short lA[2][256 * 64];  // 64 KiB
  __shared__ __align__(16) unsigned short lB[2][256 * 64];  // 64 KiB

  // bijective XCD swizzle; row-tile fastest -> per-XCD chunk shares a B panel
  const int nwg = gridDim.x;
  const int qq = nwg >> 3;
  const int wgid = (blockIdx.x & 7) * qq + (blockIdx.x >> 3);
  const int rt = wgid % NRT;
  const int ct = wgid / NRT;
  const int row0 = rt * BM;

  int e = 0;
  { int a0 = 0;
    for (int i = 0; i < NEXP; ++i) { int s = gs[i]; if (row0 < a0 + s) { e = i; break; } a0 += s; } }

  const unsigned short* Ap = A + (size_t)row0 * K;
  const unsigned short* Bg = B0m + (size_t)e * N * K;
  const unsigned short* Bu = (MODE == 0) ? (B1m + (size_t)e * N * K) : nullptr;

  const int tid  = threadIdx.x;
  const int lane = tid & 63, wave = tid >> 6;
  const int wr = wave >> 2, wc = wave & 3;   // 2 M x 4 N waves
  const int fr = lane & 15, fq = lane >> 4;

  // fragment-read slot swizzle (r4-proven): slot = (kk*4+fq) ^ (fr&7)
  const int csw0 = ((0 + fq) ^ (fr & 7)) * 8;
  const int csw1 = ((4 + fq) ^ (fr & 7)) * 8;

  // staging: sweep covers 64 rows; lane -> row srow, phys slot lane&7;
  // source column pre-swizzled so LDS(row, s) holds global slot s^(row&7)
  const int srow = wave * 8 + (lane >> 3);
  const int slog = ((lane & 7) ^ ((lane >> 3) & 7)) * 8;

  const unsigned short* aCom = Ap + (size_t)srow * K + slog;
  const unsigned short* bCom;
  if constexpr (MODE == 0) {
    const int p = (srow >> 4) & 1;                       // wave-uniform
    const int colb = ct * 128 + ((srow >> 5) << 4) + (srow & 15);
    bCom = (p ? Bu : Bg) + (size_t)colb * K + slog;
  } else {
    bCom = Bg + (size_t)(ct * 256 + srow) * K + slog;
  }
  constexpr size_t BSW = (MODE == 0) ? (size_t)32 * K : (size_t)64 * K;

  // LDS dest element offsets (wave-uniform; HW adds lane*16B)
  const int dA0 = (0   + wave * 8) * 64, dA1 = (128 + wave * 8) * 64;  // c2
  const int dA2 = (64  + wave * 8) * 64, dA3 = (192 + wave * 8) * 64;  // c3
  const int dB0 = (0   + wave * 8) * 64, dB1 = (64  + wave * 8) * 64;  // c0
  const int dB2 = (128 + wave * 8) * 64, dB3 = (192 + wave * 8) * 64;  // c1

  f32x4 acc[2][4][4] = {};
  bf16x8 aT[4], aU[4], b0[4], b1[4];

  auto stC2 = [&](int koff, unsigned short* An) {
    gload16(aCom + koff, An + dA0);
    gload16(aCom + (size_t)128 * K + koff, An + dA1);
  };
  auto stC3 = [&](int koff, unsigned short* An) {
    gload16(aCom + (size_t)64 * K + koff, An + dA2);
    gload16(aCom + (size_t)192 * K + koff, An + dA3);
  };
  auto stC0 = [&](int koff, unsigned short* Bn) {
    gload16(bCom + koff, Bn + dB0);
    gload16(bCom + BSW + koff, Bn + dB1);
  };
  auto stC1 = [&](int koff, unsigned short* Bn) {
    gload16(bCom + 2 * BSW + koff, Bn + dB2);
    gload16(bCom + 3 * BSW + koff, Bn + dB3);
  };

  auto rdA = [&](bf16x8* d, const unsigned short* Ab, int mh, int csw) {
#pragma unroll
    for (int mf = 0; mf < 4; ++mf)
      d[mf] = *(const bf16x8*)(Ab + (wr * 128 + mh * 64 + mf * 16 + fr) * 64 + csw);
  };
  auto rdB = [&](bf16x8* d, const unsigned short* Bb, int csw) {
#pragma unroll
    for (int nf = 0; nf < 4; ++nf)
      d[nf] = *(const bf16x8*)(Bb + (wc * 64 + nf * 16 + fr) * 64 + csw);
  };
  auto MF = [&](int mh, const bf16x8* a, const bf16x8* b) {
#pragma unroll
    for (int mf = 0; mf < 4; ++mf)
#pragma unroll
      for (int nf = 0; nf < 4; ++nf)
        acc[mh][mf][nf] =
            __builtin_amdgcn_mfma_f32_16x16x32_bf16(a[mf], b[nf], acc[mh][mf][nf], 0, 0, 0);
  };

  // prologue: tile 0 fully staged and published
  stC2(0, lA[0]); stC0(0, lB[0]); stC1(0, lB[0]); stC3(0, lA[0]);
  vwait(0);
  __builtin_amdgcn_s_barrier();

#pragma unroll 1
  for (int t = 0; t < nt; ++t) {
    const unsigned short* Ab = lA[t & 1];
    const unsigned short* Bb = lB[t & 1];
    unsigned short* An = lA[(t + 1) & 1];
    unsigned short* Bn = lB[(t + 1) & 1];
    const bool more = (t + 1 < nt);
    const int koff = (t + 1) * BK;

    // ---- phase 0: (mh0, kk0) ----
    rdA(aT, Ab, 0, csw0); rdB(b0, Bb, csw0);
    if (more) { stC2(koff, An); stC0(koff, Bn); }
    __builtin_amdgcn_s_barrier();
    lg0sb();
    __builtin_amdgcn_s_setprio(1);
    MF(0, aT, b0);
    __builtin_amdgcn_s_setprio(0);
    __builtin_amdgcn_s_barrier();

    // ---- phase 1: (mh0, kk1) ----
    rdA(aU, Ab, 0, csw1); rdB(b1, Bb, csw1);
    if (more) stC1(koff, Bn);
    __builtin_amdgcn_s_barrier();
    lg0sb();
    __builtin_amdgcn_s_setprio(1);
    MF(0, aU, b1);
    __builtin_amdgcn_s_setprio(0);
    vwait(more ? 6 : 0);          // drains A-c3(t); cover ~2 phases
    __builtin_amdgcn_s_barrier();

    // ---- phase 2: (mh1, kk0 + kk1), b-frags reused from regs ----
    rdA(aT, Ab, 1, csw0); rdA(aU, Ab, 1, csw1);
    if (more) stC3(koff, An);
    __builtin_amdgcn_s_barrier();
    lg0sb();
    __builtin_amdgcn_s_setprio(1);
    MF(1, aT, b0);
    MF(1, aU, b1);
    __builtin_amdgcn_s_setprio(0);
    if (more) {
      vwait(2);                   // drains c2,c0,c1(t+1); keeps c3(t+1) flying
      __builtin_amdgcn_s_barrier();
    }
  }

  // epilogue. C/D frag layout: col = lane&15, row = fq*4 + reg (m89-verified)
#pragma unroll
  for (int mh = 0; mh < 2; ++mh) {
#pragma unroll
    for (int mf = 0; mf < 4; ++mf) {
      const int rowb = row0 + wr * 128 + mh * 64 + mf * 16 + fq * 4;
      if constexpr (MODE == 0) {
#pragma unroll
        for (int m2 = 0; m2 < 2; ++m2) {
          const int col = ct * 128 + (wc * 2 + m2) * 16 + fr;
          f32x4 g = acc[mh][mf][2 * m2], u = acc[mh][mf][2 * m2 + 1];
#pragma unroll
          for (int r = 0; r < 4; ++r) {
            float gv = g[r];
            Hc[(size_t)(rowb + r) * N + col] = f2bf(gv / (1.f + __expf(-gv)) * u[r]);
          }
        }
      } else {
#pragma unroll
        for (int nf = 0; nf < 4; ++nf) {
          const int col = ct * 256 + wc * 64 + nf * 16 + fr;
          f32x4 v = acc[mh][mf][nf];
#pragma unroll
          for (int r = 0; r < 4; ++r)
            Cf[(size_t)(rowb + r) * N + col] = v[r];
        }
      }
    }
  }
}

extern "C" void kernel_launch(void* const* d_in, const int* in_sizes, int n_in,
                              void* d_out, int out_size, void* d_ws, size_t ws_size,
                              hipStream_t stream)
{
  const float* x  = (const float*)d_in[0];
  const float* wg = (const float*)d_in[1];
  const float* wu = (const float*)d_in[2];
  const float* wd = (const float*)d_in[3];
  const int*   gs = (const int*)d_in[4];
  float* out = (float*)d_out;

  const size_t SZ_XB = (size_t)TOKENS * HID * 2;        // 134,217,728
  const size_t SZ_W  = (size_t)NEXP * HID * IMD * 2;    //  92,274,688
  const size_t SZ_H  = (size_t)TOKENS * IMD * 2;        //  92,274,688
  if (ws_size < SZ_XB + 2 * SZ_W + SZ_H) return;        // (411 MB proven available)

  char* ws = (char*)d_ws;
  unsigned short* xb  = (unsigned short*)ws;
  unsigned short* wTg = (unsigned short*)(ws + SZ_XB);
  unsigned short* wTu = (unsigned short*)(ws + SZ_XB + SZ_W);
  unsigned short* h   = (unsigned short*)(ws + SZ_XB + 2 * SZ_W);

  const int cvt_grid = (int)(((size_t)TOKENS * HID) / (256 * 8));
  convert_kernel<<<cvt_grid, 256, 0, stream>>>(x, xb, (size_t)TOKENS * HID);

  transpose_conv_kernel<<<dim3(IMD / 32, HID / 32, NEXP), dim3(32, 8), 0, stream>>>(wg, wTg, HID, IMD);
  transpose_conv_kernel<<<dim3(IMD / 32, HID / 32, NEXP), dim3(32, 8), 0, stream>>>(wu, wTu, HID, IMD);
  gemm_kernel<0, HID, IMD><<<(TOKENS / BM) * (IMD / 128), 512, 0, stream>>>(
      xb, wTg, wTu, h, nullptr, gs);

  transpose_conv_kernel<<<dim3(HID / 32, IMD / 32, NEXP), dim3(32, 8), 0, stream>>>(wd, wTg, IMD, HID);
  gemm_kernel<1, IMD, HID><<<(TOKENS / BM) * (HID / 256), 512, 0, stream>>>(
      h, wTg, nullptr, nullptr, out, gs);
}